// Round 1
// baseline (2301.582 us; speedup 1.0000x reference)
//
#include <hip/hip_runtime.h>

#define NROWS 8192
#define DIM   512
#define BM 128
#define BN 128
#define BK 32

// ---------------- norms: one wave per row ----------------
__global__ __launch_bounds__(256) void norms_kernel(const float* __restrict__ x,
                                                    const float* __restrict__ y,
                                                    float* __restrict__ xn,
                                                    float* __restrict__ yn) {
    int gw   = (blockIdx.x * blockDim.x + threadIdx.x) >> 6;  // global wave id
    int lane = threadIdx.x & 63;
    if (gw >= 2 * NROWS) return;
    const float* src = (gw < NROWS) ? x : y;
    float*       dst = (gw < NROWS) ? xn : yn;
    int row = (gw < NROWS) ? gw : gw - NROWS;
    const float* p = src + (size_t)row * DIM;
    float s = 0.f;
    #pragma unroll
    for (int k = 0; k < DIM / 64; ++k) {
        float v = p[lane + k * 64];
        s += v * v;
    }
    #pragma unroll
    for (int off = 32; off > 0; off >>= 1) s += __shfl_down(s, off, 64);
    if (lane == 0) dst[row] = s;
}

// ---------------- zero the fp64 accumulator ----------------
__global__ void zero_kernel(double* acc) {
    if (threadIdx.x == 0 && blockIdx.x == 0) *acc = 0.0;
}

// ---------------- fused pairwise-distance + kernel-sum ----------------
// blockIdx.z: 0 = k(x,x), 1 = k(y,y), 2 = k(x,y)  (weight -2)
__global__ __launch_bounds__(256) void mmd_kernel(const float* __restrict__ X,
                                                  const float* __restrict__ Y,
                                                  const float* __restrict__ xn,
                                                  const float* __restrict__ yn,
                                                  double* __restrict__ acc) {
    __shared__ float As[BK][BM + 4];
    __shared__ float Bs[BK][BN + 4];

    const int p = blockIdx.z;
    const float* A  = (p == 1) ? Y : X;
    const float* B  = (p == 0) ? X : Y;
    const float* an = (p == 1) ? yn : xn;
    const float* bn = (p == 0) ? xn : yn;
    const float wgt = (p == 2) ? -2.0f : 1.0f;

    const int bm = blockIdx.x * BM;
    const int bnc = blockIdx.y * BN;
    const int tid = threadIdx.x;
    const int tx = tid & 15;   // col group, 16 x 8 = 128
    const int ty = tid >> 4;   // row group

    float accf[8][8];
    #pragma unroll
    for (int i = 0; i < 8; ++i)
        #pragma unroll
        for (int j = 0; j < 8; ++j) accf[i][j] = 0.f;

    for (int k0 = 0; k0 < DIM; k0 += BK) {
        // stage A,B tiles (128x32 each) transposed into LDS
        #pragma unroll
        for (int i = 0; i < 4; ++i) {
            int id = tid + i * 256;          // 0..1023 float4 slots
            int r  = id >> 3;                // 0..127
            int c  = (id & 7) * 4;           // 0..28
            float4 va = *(const float4*)(A + (size_t)(bm + r) * DIM + k0 + c);
            As[c + 0][r] = va.x; As[c + 1][r] = va.y;
            As[c + 2][r] = va.z; As[c + 3][r] = va.w;
            float4 vb = *(const float4*)(B + (size_t)(bnc + r) * DIM + k0 + c);
            Bs[c + 0][r] = vb.x; Bs[c + 1][r] = vb.y;
            Bs[c + 2][r] = vb.z; Bs[c + 3][r] = vb.w;
        }
        __syncthreads();

        #pragma unroll
        for (int kk = 0; kk < BK; ++kk) {
            float a[8], b[8];
            // vectorized LDS reads (16B-aligned: stride 132 floats, kk*132*4 % 16 == 0)
            float4 a0 = *(const float4*)&As[kk][ty * 8];
            float4 a1 = *(const float4*)&As[kk][ty * 8 + 4];
            float4 b0 = *(const float4*)&Bs[kk][tx * 8];
            float4 b1 = *(const float4*)&Bs[kk][tx * 8 + 4];
            a[0]=a0.x; a[1]=a0.y; a[2]=a0.z; a[3]=a0.w;
            a[4]=a1.x; a[5]=a1.y; a[6]=a1.z; a[7]=a1.w;
            b[0]=b0.x; b[1]=b0.y; b[2]=b0.z; b[3]=b0.w;
            b[4]=b1.x; b[5]=b1.y; b[6]=b1.z; b[7]=b1.w;
            #pragma unroll
            for (int i = 0; i < 8; ++i)
                #pragma unroll
                for (int j = 0; j < 8; ++j)
                    accf[i][j] = __fmaf_rn(a[i], b[j], accf[i][j]);
        }
        __syncthreads();
    }

    // epilogue: dxy -> sum of 3-bandwidth gaussian kernels
    float lsum = 0.f;
    #pragma unroll
    for (int i = 0; i < 8; ++i) {
        float anr = an[bm + ty * 8 + i];
        #pragma unroll
        for (int j = 0; j < 8; ++j) {
            float dxy = anr + bn[bnc + tx * 8 + j] - 2.0f * accf[i][j];
            lsum += __expf(-0.5f * dxy)
                  + __expf(-0.25f * dxy)
                  + __expf(-0.16666666666666666f * dxy);
        }
    }

    // block reduce (4 waves)
    #pragma unroll
    for (int off = 32; off > 0; off >>= 1) lsum += __shfl_down(lsum, off, 64);
    __shared__ float wsum[4];
    int wid = tid >> 6, lane = tid & 63;
    __syncthreads();
    if (lane == 0) wsum[wid] = lsum;
    __syncthreads();
    if (tid == 0) {
        float bs = wsum[0] + wsum[1] + wsum[2] + wsum[3];
        atomicAdd(acc, (double)bs * (double)wgt);
    }
}

// ---------------- finalize ----------------
__global__ void finalize_kernel(const double* __restrict__ acc, float* __restrict__ out) {
    if (threadIdx.x == 0 && blockIdx.x == 0) {
        double n2 = (double)NROWS * (double)NROWS;
        out[0] = (float)(*acc / n2);
    }
}

extern "C" void kernel_launch(void* const* d_in, const int* in_sizes, int n_in,
                              void* d_out, int out_size, void* d_ws, size_t ws_size,
                              hipStream_t stream) {
    const float* x = (const float*)d_in[0];
    const float* y = (const float*)d_in[1];
    float* out = (float*)d_out;

    char* ws = (char*)d_ws;
    float* xn = (float*)ws;                      // 8192 floats
    float* yn = (float*)(ws + NROWS * 4);        // 8192 floats
    double* acc = (double*)(ws + 64 * 1024);     // 1 double, 64KB-aligned region

    zero_kernel<<<1, 64, 0, stream>>>(acc);
    norms_kernel<<<(2 * NROWS) / 4, 256, 0, stream>>>(x, y, xn, yn);

    dim3 grid(NROWS / BM, NROWS / BN, 3);
    mmd_kernel<<<grid, 256, 0, stream>>>(x, y, xn, yn, acc);

    finalize_kernel<<<1, 64, 0, stream>>>(acc, out);
}

// Round 2
// 257.013 us; speedup vs baseline: 8.9551x; 8.9551x over previous
//
#include <hip/hip_runtime.h>

#define NR  8192
#define DIM 512
#define BM  128
#define BK  64

typedef __attribute__((ext_vector_type(8))) short bf16x8;
typedef __attribute__((ext_vector_type(4))) float f32x4;
typedef unsigned short u16;
typedef unsigned int   u32;

// ---- async global->LDS, 16B per lane, wave-uniform LDS base ----
__device__ __forceinline__ void gload16(const void* g, void* l) {
    __builtin_amdgcn_global_load_lds((const __attribute__((address_space(1))) void*)g,
                                     (__attribute__((address_space(3))) void*)l,
                                     16, 0, 0);
}

// ================= convert fp32 -> bf16 + norms (of bf16 values) =================
__global__ __launch_bounds__(256) void conv_kernel(const float* __restrict__ x,
                                                   const float* __restrict__ y,
                                                   u16* __restrict__ xb, u16* __restrict__ yb,
                                                   float* __restrict__ xn, float* __restrict__ yn) {
    int gw   = (blockIdx.x * 256 + threadIdx.x) >> 6;
    int lane = threadIdx.x & 63;
    if (gw >= 2 * NR) return;
    int row = (gw < NR) ? gw : gw - NR;
    const float* src = (gw < NR) ? x : y;
    u16*   dst = (gw < NR) ? xb : yb;
    float* nrm = (gw < NR) ? xn : yn;

    const float4* p = (const float4*)(src + (size_t)row * DIM);
    float4 v0 = p[lane * 2], v1 = p[lane * 2 + 1];
    float vv[8] = {v0.x, v0.y, v0.z, v0.w, v1.x, v1.y, v1.z, v1.w};
    u16 us[8];
    float s = 0.f;
    #pragma unroll
    for (int i = 0; i < 8; ++i) {
        u32 u = __float_as_uint(vv[i]);
        u16 b = (u16)((u + 0x7FFFu + ((u >> 16) & 1u)) >> 16);   // RNE fp32->bf16
        us[i] = b;
        float bf = __uint_as_float(((u32)b) << 16);
        s += bf * bf;
    }
    *(bf16x8*)(dst + (size_t)row * DIM + lane * 8) = *(const bf16x8*)us;
    #pragma unroll
    for (int off = 32; off; off >>= 1) s += __shfl_down(s, off, 64);
    if (lane == 0) nrm[row] = s;
}

// ================= zero accumulator =================
__global__ void zero_kernel(double* acc) {
    if (threadIdx.x == 0 && blockIdx.x == 0) *acc = 0.0;
}

// ================= MFMA fused pairwise kernel-sum =================
// grid (64,64,3): z=0 k(x,x) upper-tri, z=1 k(y,y) upper-tri, z=2 k(x,y) full (weight -2)
__global__ __launch_bounds__(256) void mmd_mfma(const u16* __restrict__ xb, const u16* __restrict__ yb,
                                                const float* __restrict__ xn, const float* __restrict__ yn,
                                                double* __restrict__ acc) {
    const int z  = blockIdx.z;
    const int bi = blockIdx.x, bj = blockIdx.y;
    if (z < 2 && bj < bi) return;   // symmetry: upper triangle only for xx, yy
    const u16*   A  = (z == 1) ? yb : xb;
    const u16*   B  = (z == 0) ? xb : yb;
    const float* an = (z == 1) ? yn : xn;
    const float* bn = (z == 0) ? xn : yn;
    const float wgt = (z == 2) ? -2.f : ((bi == bj) ? 1.f : 2.f);
    const int bm  = bi * BM;
    const int bnc = bj * BM;

    __shared__ __align__(16) u16 As[BM * BK];
    __shared__ __align__(16) u16 Bs[BM * BK];

    const int tid  = threadIdx.x;
    const int w    = tid >> 6, lane = tid & 63;
    const int wm   = w >> 1,   wn   = w & 1;      // 2x2 wave grid, 64x64 out each

    // staging lane constants: lane covers (row = 8q + srow, 16B slot dslot)
    const int srow  = lane >> 3;                  // 0..7
    const int dslot = (lane & 7) ^ srow;          // pre-swizzled source slot

    // fragment lane constants
    const int fr = lane & 15;                     // row within 16x16 frag
    const int kg = lane >> 4;                     // k-group 0..3
    const int sw = lane & 7;                      // read-side XOR

    f32x4 acc4[4][4];
    #pragma unroll
    for (int i = 0; i < 4; ++i)
        #pragma unroll
        for (int j = 0; j < 4; ++j)
            acc4[i][j] = {0.f, 0.f, 0.f, 0.f};

    for (int k0 = 0; k0 < DIM; k0 += BK) {
        // ---- stage A,B 128x64 bf16 tiles; LDS linear [row][64], source pre-swizzled ----
        #pragma unroll
        for (int q = 0; q < 4; ++q) {
            const int rbase = w * 32 + q * 8;
            const int r     = rbase + srow;
            gload16(A + (size_t)(bm  + r) * DIM + k0 + dslot * 8, As + rbase * 64);
            gload16(B + (size_t)(bnc + r) * DIM + k0 + dslot * 8, Bs + rbase * 64);
        }
        __syncthreads();

        // ---- 2 x K=32 MFMA steps ----
        #pragma unroll
        for (int kk2 = 0; kk2 < 2; ++kk2) {
            const int c  = kk2 * 4 + kg;          // 16B col slot
            const int cs = ((c ^ sw) * 8);        // swizzled read offset (elements)
            bf16x8 af[4], bfv[4];
            #pragma unroll
            for (int fm = 0; fm < 4; ++fm)
                af[fm] = *(const bf16x8*)(As + (wm * 64 + fm * 16 + fr) * 64 + cs);
            #pragma unroll
            for (int fn = 0; fn < 4; ++fn)
                bfv[fn] = *(const bf16x8*)(Bs + (wn * 64 + fn * 16 + fr) * 64 + cs);
            #pragma unroll
            for (int fm = 0; fm < 4; ++fm)
                #pragma unroll
                for (int fn = 0; fn < 4; ++fn)
                    acc4[fm][fn] = __builtin_amdgcn_mfma_f32_16x16x32_bf16(af[fm], bfv[fn], acc4[fm][fn], 0, 0, 0);
        }
        __syncthreads();
    }

    // ---- epilogue: d = an + bn - 2*dot ; sum of 3 gaussians via t = exp(-d/12) ----
    float lsum = 0.f;
    #pragma unroll
    for (int fm = 0; fm < 4; ++fm) {
        const f32x4 anv = *(const f32x4*)(an + bm + wm * 64 + fm * 16 + kg * 4);
        #pragma unroll
        for (int fn = 0; fn < 4; ++fn) {
            const float bnv = bn[bnc + wn * 64 + fn * 16 + fr];
            #pragma unroll
            for (int j = 0; j < 4; ++j) {
                float d  = anv[j] + bnv - 2.0f * acc4[fm][fn][j];
                float t  = __expf(d * (-1.0f / 12.0f));
                float t2 = t * t, t3 = t2 * t;
                lsum += t2 + t3 + t3 * t3;        // bw3 + bw2 + bw1
            }
        }
    }

    #pragma unroll
    for (int off = 32; off; off >>= 1) lsum += __shfl_down(lsum, off, 64);
    __shared__ float wsum[4];
    if (lane == 0) wsum[w] = lsum;
    __syncthreads();
    if (tid == 0)
        atomicAdd(acc, (double)((wsum[0] + wsum[1] + wsum[2] + wsum[3]) * wgt));
}

// ================= finalize =================
__global__ void finalize_kernel(const double* __restrict__ acc, float* __restrict__ out) {
    if (threadIdx.x == 0 && blockIdx.x == 0) {
        double n2 = (double)NR * (double)NR;
        out[0] = (float)(*acc / n2);
    }
}

// ================= fp32 fallback (round-1 kernel, used only if ws too small) =================
__global__ __launch_bounds__(256) void norms_f32(const float* __restrict__ x, const float* __restrict__ y,
                                                 float* __restrict__ xn, float* __restrict__ yn) {
    int gw = (blockIdx.x * blockDim.x + threadIdx.x) >> 6;
    int lane = threadIdx.x & 63;
    if (gw >= 2 * NR) return;
    const float* src = (gw < NR) ? x : y;
    float* dst = (gw < NR) ? xn : yn;
    int row = (gw < NR) ? gw : gw - NR;
    const float* p = src + (size_t)row * DIM;
    float s = 0.f;
    #pragma unroll
    for (int k = 0; k < DIM / 64; ++k) { float v = p[lane + k * 64]; s += v * v; }
    #pragma unroll
    for (int off = 32; off; off >>= 1) s += __shfl_down(s, off, 64);
    if (lane == 0) dst[row] = s;
}

__global__ __launch_bounds__(256) void mmd_f32(const float* __restrict__ X, const float* __restrict__ Y,
                                               const float* __restrict__ xn, const float* __restrict__ yn,
                                               double* __restrict__ acc) {
    __shared__ float Asf[32][BM + 4];
    __shared__ float Bsf[32][BM + 4];
    const int p = blockIdx.z;
    const float* A  = (p == 1) ? Y : X;
    const float* B  = (p == 0) ? X : Y;
    const float* an = (p == 1) ? yn : xn;
    const float* bn = (p == 0) ? xn : yn;
    const float wgt = (p == 2) ? -2.0f : 1.0f;
    const int bm = blockIdx.x * BM, bnc = blockIdx.y * BM;
    const int tid = threadIdx.x, tx = tid & 15, ty = tid >> 4;
    float accf[8][8];
    #pragma unroll
    for (int i = 0; i < 8; ++i)
        #pragma unroll
        for (int j = 0; j < 8; ++j) accf[i][j] = 0.f;
    for (int k0 = 0; k0 < DIM; k0 += 32) {
        #pragma unroll
        for (int i = 0; i < 4; ++i) {
            int id = tid + i * 256, r = id >> 3, c = (id & 7) * 4;
            float4 va = *(const float4*)(A + (size_t)(bm + r) * DIM + k0 + c);
            Asf[c+0][r]=va.x; Asf[c+1][r]=va.y; Asf[c+2][r]=va.z; Asf[c+3][r]=va.w;
            float4 vb = *(const float4*)(B + (size_t)(bnc + r) * DIM + k0 + c);
            Bsf[c+0][r]=vb.x; Bsf[c+1][r]=vb.y; Bsf[c+2][r]=vb.z; Bsf[c+3][r]=vb.w;
        }
        __syncthreads();
        #pragma unroll
        for (int kk = 0; kk < 32; ++kk) {
            float a[8], b[8];
            float4 a0 = *(const float4*)&Asf[kk][ty*8], a1 = *(const float4*)&Asf[kk][ty*8+4];
            float4 b0 = *(const float4*)&Bsf[kk][tx*8], b1 = *(const float4*)&Bsf[kk][tx*8+4];
            a[0]=a0.x;a[1]=a0.y;a[2]=a0.z;a[3]=a0.w;a[4]=a1.x;a[5]=a1.y;a[6]=a1.z;a[7]=a1.w;
            b[0]=b0.x;b[1]=b0.y;b[2]=b0.z;b[3]=b0.w;b[4]=b1.x;b[5]=b1.y;b[6]=b1.z;b[7]=b1.w;
            #pragma unroll
            for (int i = 0; i < 8; ++i)
                #pragma unroll
                for (int j = 0; j < 8; ++j)
                    accf[i][j] = __fmaf_rn(a[i], b[j], accf[i][j]);
        }
        __syncthreads();
    }
    float lsum = 0.f;
    #pragma unroll
    for (int i = 0; i < 8; ++i) {
        float anr = an[bm + ty * 8 + i];
        #pragma unroll
        for (int j = 0; j < 8; ++j) {
            float d = anr + bn[bnc + tx * 8 + j] - 2.0f * accf[i][j];
            float t = __expf(d * (-1.0f / 12.0f));
            float t2 = t * t, t3 = t2 * t;
            lsum += t2 + t3 + t3 * t3;
        }
    }
    #pragma unroll
    for (int off = 32; off; off >>= 1) lsum += __shfl_down(lsum, off, 64);
    __shared__ float wsumf[4];
    int wd = tid >> 6, ln = tid & 63;
    if (ln == 0) wsumf[wd] = lsum;
    __syncthreads();
    if (tid == 0) atomicAdd(acc, (double)((wsumf[0]+wsumf[1]+wsumf[2]+wsumf[3]) * wgt));
}

// ================= launch =================
extern "C" void kernel_launch(void* const* d_in, const int* in_sizes, int n_in,
                              void* d_out, int out_size, void* d_ws, size_t ws_size,
                              hipStream_t stream) {
    const float* x = (const float*)d_in[0];
    const float* y = (const float*)d_in[1];
    float* out = (float*)d_out;
    char* ws = (char*)d_ws;

    const size_t bfBytes = (size_t)NR * DIM * 2;          // 8 MiB each
    const size_t need = 2 * bfBytes + 2 * (size_t)NR * 4 + 1024;

    if (ws_size >= need) {
        u16*   xbuf = (u16*)ws;
        u16*   ybuf = (u16*)(ws + bfBytes);
        float* xn   = (float*)(ws + 2 * bfBytes);
        float* yn   = (float*)(ws + 2 * bfBytes + (size_t)NR * 4);
        double* acc = (double*)(ws + 2 * bfBytes + 2 * (size_t)NR * 4);

        zero_kernel<<<1, 64, 0, stream>>>(acc);
        conv_kernel<<<(2 * NR) / 4, 256, 0, stream>>>(x, y, xbuf, ybuf, xn, yn);
        dim3 grid(NR / BM, NR / BM, 3);
        mmd_mfma<<<grid, 256, 0, stream>>>(xbuf, ybuf, xn, yn, acc);
        finalize_kernel<<<1, 64, 0, stream>>>(acc, out);
    } else {
        float* xn = (float*)ws;
        float* yn = (float*)(ws + (size_t)NR * 4);
        double* acc = (double*)(ws + 64 * 1024);
        zero_kernel<<<1, 64, 0, stream>>>(acc);
        norms_f32<<<(2 * NR) / 4, 256, 0, stream>>>(x, y, xn, yn);
        dim3 grid(NR / BM, NR / BM, 3);
        mmd_f32<<<grid, 256, 0, stream>>>(x, y, xn, yn, acc);
        finalize_kernel<<<1, 64, 0, stream>>>(acc, out);
    }
}